// Round 1
// baseline (370.075 us; speedup 1.0000x reference)
//
#include <hip/hip_runtime.h>
#include <cstdint>

// Problem constants (fixed by reference setup_inputs):
//   N = 200000, M = 64 (== wavefront), D = 256, K = 3
#define D_DIM 256
#define M_DIM 64
#define K_TOP 3

// Kernel 1: per-node dual dot product.
// One wave (64 lanes) per node row. Each lane loads float4 (16B) -> 64*16B = 1KB row,
// perfectly coalesced. W (512 floats) is broadcast-cached.
__global__ __launch_bounds__(256) void ns_scores_kernel(
    const float* __restrict__ nf,      // (N, 256)
    const float* __restrict__ W,       // (512,)
    const float* __restrict__ b,       // (1,)
    float* __restrict__ s_self,        // (N,)
    float* __restrict__ s_all,         // (N,)
    int N)
{
    const int gtid = blockIdx.x * blockDim.x + threadIdx.x;
    const int row  = gtid >> 6;
    const int lane = threadIdx.x & 63;
    if (row >= N) return;

    const float4 v  = ((const float4*)(nf + (size_t)row * D_DIM))[lane];
    const float4 wa = ((const float4*)W)[lane];
    const float4 wb = ((const float4*)(W + D_DIM))[lane];

    float sa = v.x * wa.x + v.y * wa.y + v.z * wa.z + v.w * wa.w;
    float sb = v.x * wb.x + v.y * wb.y + v.z * wb.z + v.w * wb.w;

    // wave-64 reduce
    #pragma unroll
    for (int off = 32; off > 0; off >>= 1) {
        sa += __shfl_down(sa, off);
        sb += __shfl_down(sb, off);
    }
    if (lane == 0) {
        s_self[row] = sa + b[0];
        s_all[row]  = sb;
    }
}

// Kernel 2: per-node score + top-3.
// One wave per node; lane j handles neighbor j (M == 64 == wave width).
// Tie-break matches jax.lax.top_k: equal value -> lower index first.
// All valid scores are exp(...) > 0, so 0.0f is a safe invalid/knockout
// sentinel and positive-float bit patterns are monotone as unsigned.
__global__ __launch_bounds__(256) void ns_topk_kernel(
    const int* __restrict__ neighbors, // (N, 64) int32
    const int* __restrict__ counts,    // (N,)    int32
    const float* __restrict__ s_self,  // (N,)
    const float* __restrict__ s_all,   // (N,)
    float* __restrict__ out_vals,      // (N, 3)
    float* __restrict__ out_idx,       // (N, 3)  indices as float
    int N)
{
    const int gtid = blockIdx.x * blockDim.x + threadIdx.x;
    const int row  = gtid >> 6;
    const int lane = threadIdx.x & 63;
    if (row >= N) return;

    const int nbr = neighbors[(size_t)row * M_DIM + lane];
    const int cnt = counts[row];
    const float ss = s_self[row];

    float score = 0.0f;
    if (lane < cnt) {
        const float x  = ss + s_all[nbr];
        const float lr = (x >= 0.0f) ? x : 0.01f * x;
        score = expf(lr);
    }

    // key = (score_bits << 32) | (63 - lane): max key == max score, tie -> min lane
    unsigned long long key =
        ((unsigned long long)__float_as_uint(score) << 32) |
        (unsigned long long)(63 - lane);

    float vals[K_TOP];
    int   idxs[K_TOP];

    #pragma unroll
    for (int k = 0; k < K_TOP; ++k) {
        unsigned long long m = key;
        #pragma unroll
        for (int off = 32; off > 0; off >>= 1) {
            const unsigned long long o = __shfl_xor(m, off);
            if (o > m) m = o;
        }
        const int jwin = 63 - (int)(m & 0xFFFFFFFFull);
        vals[k] = __uint_as_float((unsigned)(m >> 32));
        idxs[k] = __shfl(nbr, jwin);
        if (lane == jwin) {
            // knock out: zero the value bits, keep lane tag
            key = (unsigned long long)(63 - lane);
        }
    }

    if (lane == 0) {
        const size_t base = (size_t)row * K_TOP;
        #pragma unroll
        for (int k = 0; k < K_TOP; ++k) {
            out_vals[base + k] = vals[k];
            out_idx [base + k] = (float)idxs[k];
        }
    }
}

extern "C" void kernel_launch(void* const* d_in, const int* in_sizes, int n_in,
                              void* d_out, int out_size, void* d_ws, size_t ws_size,
                              hipStream_t stream)
{
    const float* nf        = (const float*)d_in[0];   // (N, 256)
    const int*   neighbors = (const int*)  d_in[1];   // (N, 64)
    const int*   counts    = (const int*)  d_in[2];   // (N,)
    const float* W         = (const float*)d_in[3];   // (512,)
    const float* b         = (const float*)d_in[4];   // (1,)

    const int N = in_sizes[2];                        // neighbor_counts count

    float* s_self = (float*)d_ws;                     // N floats
    float* s_all  = s_self + N;                       // N floats

    float* out_vals = (float*)d_out;                  // N*3
    float* out_idx  = out_vals + (size_t)N * K_TOP;   // N*3 (indices as float)

    const int threads = 256;                          // 4 waves/block
    const int wavesPerBlock = threads / 64;
    const int blocks = (N + wavesPerBlock - 1) / wavesPerBlock;

    ns_scores_kernel<<<blocks, threads, 0, stream>>>(nf, W, b, s_self, s_all, N);
    ns_topk_kernel<<<blocks, threads, 0, stream>>>(neighbors, counts, s_self, s_all,
                                                   out_vals, out_idx, N);
}

// Round 2
// 339.465 us; speedup vs baseline: 1.0902x; 1.0902x over previous
//
#include <hip/hip_runtime.h>
#include <cstdint>

// Problem constants (fixed by reference setup_inputs):
//   N = 200000, M = 64, D = 256, K = 3
#define D_DIM 256
#define M_DIM 64
#define K_TOP 3

typedef unsigned long long u64;

// Kernel 1: per-node dual dot product. 4 rows per wave, 16 lanes per row.
// Each lane loads 4x float4 (64B) from its row; reduction needs only
// 4 shfl_xor steps within the 16-lane group (2 shuffles/row amortized,
// vs 12/row for the wave-per-row version).
__global__ __launch_bounds__(256) void ns_scores_kernel(
    const float* __restrict__ nf,      // (N, 256)
    const float* __restrict__ W,       // (512,)
    const float* __restrict__ b,       // (1,)
    float* __restrict__ s_self,        // (N,)
    float* __restrict__ s_all,         // (N,)
    int N)
{
    const int wave = (blockIdx.x * blockDim.x + threadIdx.x) >> 6;
    const int lane = threadIdx.x & 63;
    const int sub  = lane >> 4;        // which row within the wave's group of 4
    const int p    = lane & 15;        // position within the 16-lane row team
    const int row  = wave * 4 + sub;
    if (row >= N) return;

    const float4* __restrict__ vrow = (const float4*)(nf + (size_t)row * D_DIM);
    const float4* __restrict__ wa4  = (const float4*)W;
    const float4* __restrict__ wb4  = (const float4*)(W + D_DIM);

    float sa = 0.0f, sb = 0.0f;
    #pragma unroll
    for (int i = 0; i < 4; ++i) {
        const int o = i * 16 + p;
        const float4 v = vrow[o];
        const float4 a = wa4[o];
        const float4 c = wb4[o];
        sa += v.x * a.x + v.y * a.y + v.z * a.z + v.w * a.w;
        sb += v.x * c.x + v.y * c.y + v.z * c.z + v.w * c.w;
    }

    // reduce within the 16-lane team (xor offsets stay inside the team)
    #pragma unroll
    for (int off = 8; off > 0; off >>= 1) {
        sa += __shfl_xor(sa, off);
        sb += __shfl_xor(sb, off);
    }
    if (p == 0) {
        s_self[row] = sa + b[0];
        s_all[row]  = sb;
    }
}

// Kernel 2: per-node score + top-3. 4 rows per wave; lane p holds the row's
// neighbors 4p..4p+3 via one int4 load (16B/lane, 1KB/wave coalesced).
// Tie-break matches jax.lax.top_k (equal value -> lower index): key packs
// (score_bits << 32) | (63 - j); all valid scores exp(...) > 0 so zeroed
// score bits are a safe knockout sentinel.
__global__ __launch_bounds__(256) void ns_topk_kernel(
    const int* __restrict__ neighbors, // (N, 64) int32
    const int* __restrict__ counts,    // (N,)    int32
    const float* __restrict__ s_self,  // (N,)
    const float* __restrict__ s_all,   // (N,)
    float* __restrict__ out_vals,      // (N, 3)
    float* __restrict__ out_idx,       // (N, 3)  indices as float
    int N)
{
    const int wave = (blockIdx.x * blockDim.x + threadIdx.x) >> 6;
    const int lane = threadIdx.x & 63;
    const int sub  = lane >> 4;
    const int p    = lane & 15;
    const int row  = wave * 4 + sub;
    if (row >= N) return;

    const int4 nb = ((const int4*)(neighbors + (size_t)row * M_DIM))[p];
    const int  cnt = counts[row];     // uniform within team -> HW broadcast
    const float ss = s_self[row];

    const int nbs[4] = { nb.x, nb.y, nb.z, nb.w };
    u64 key[4];
    #pragma unroll
    for (int e = 0; e < 4; ++e) {
        const int j = p * 4 + e;
        float score = 0.0f;
        if (j < cnt) {
            const float x  = ss + s_all[nbs[e]];
            const float lr = (x >= 0.0f) ? x : 0.01f * x;
            score = expf(lr);
        }
        key[e] = ((u64)__float_as_uint(score) << 32) | (u64)(63 - j);
    }

    float vals[K_TOP];
    int   idxs[K_TOP];

    #pragma unroll
    for (int k = 0; k < K_TOP; ++k) {
        u64 m = key[0];
        if (key[1] > m) m = key[1];
        if (key[2] > m) m = key[2];
        if (key[3] > m) m = key[3];
        #pragma unroll
        for (int off = 8; off > 0; off >>= 1) {
            const u64 o = __shfl_xor(m, off);
            if (o > m) m = o;
        }
        const int jwin = 63 - (int)(m & 0x3F);
        vals[k] = __uint_as_float((unsigned)(m >> 32));

        const int ew = jwin & 3;       // element within owner's int4
        const int pw = jwin >> 2;      // owner lane within team
        const int cand = (ew == 0) ? nbs[0] : (ew == 1) ? nbs[1]
                       : (ew == 2) ? nbs[2] : nbs[3];
        idxs[k] = __shfl(cand, (sub << 4) | pw);

        if (p == pw) {                 // owner knocks out the winning element
            const u64 dead = (u64)(63 - jwin);
            if      (ew == 0) key[0] = dead;
            else if (ew == 1) key[1] = dead;
            else if (ew == 2) key[2] = dead;
            else              key[3] = dead;
        }
    }

    if (p == 0) {
        const size_t base = (size_t)row * K_TOP;
        #pragma unroll
        for (int k = 0; k < K_TOP; ++k) {
            out_vals[base + k] = vals[k];
            out_idx [base + k] = (float)idxs[k];
        }
    }
}

extern "C" void kernel_launch(void* const* d_in, const int* in_sizes, int n_in,
                              void* d_out, int out_size, void* d_ws, size_t ws_size,
                              hipStream_t stream)
{
    const float* nf        = (const float*)d_in[0];   // (N, 256)
    const int*   neighbors = (const int*)  d_in[1];   // (N, 64)
    const int*   counts    = (const int*)  d_in[2];   // (N,)
    const float* W         = (const float*)d_in[3];   // (512,)
    const float* b         = (const float*)d_in[4];   // (1,)

    const int N = in_sizes[2];

    float* s_self = (float*)d_ws;                     // N floats
    float* s_all  = s_self + N;                       // N floats

    float* out_vals = (float*)d_out;                  // N*3
    float* out_idx  = out_vals + (size_t)N * K_TOP;   // N*3 (indices as float)

    const int threads = 256;                          // 4 waves -> 16 rows/block
    const int rowsPerBlock = (threads / 64) * 4;
    const int blocks = (N + rowsPerBlock - 1) / rowsPerBlock;

    ns_scores_kernel<<<blocks, threads, 0, stream>>>(nf, W, b, s_self, s_all, N);
    ns_topk_kernel<<<blocks, threads, 0, stream>>>(neighbors, counts, s_self, s_all,
                                                   out_vals, out_idx, N);
}